// Round 13
// baseline (292.704 us; speedup 1.0000x reference)
//
#include <hip/hip_runtime.h>

// ---------------------------------------------------------------------------
// MultiHeadedDotProductSelfAttention: B=2, S=2048, D=2048, H=16, dh=128
// R13: exact R8 configuration (no XCD swizzle — default round-robin is
// L2-optimal for this grid) + V transposed inside the GEMM epilogue via a
// 16KB LDS tile with coalesced global writes (transpose_v dispatch removed).
// ---------------------------------------------------------------------------

typedef __attribute__((ext_vector_type(8))) short bfx8;
typedef __attribute__((ext_vector_type(4))) float f32x4;

#define TO_GLOBAL(p) ((const __attribute__((address_space(1))) void*)(p))
#define TO_LDS(p)    ((__attribute__((address_space(3))) void*)(p))

__device__ __forceinline__ unsigned short f2bf(float f) {
    unsigned int u = __float_as_uint(f);
    u += 0x7FFFu + ((u >> 16) & 1u);          // round-to-nearest-even
    return (unsigned short)(u >> 16);
}

__device__ __forceinline__ void store_out(unsigned short* p, float v) { *p = f2bf(v); }
__device__ __forceinline__ void store_out(float* p, float v) { *p = v; }

// ---------------------------------------------------------------- cast kernels
__global__ void cast_bf16_kernel(const float* __restrict__ x,
                                 unsigned short* __restrict__ y, int n4) {
    int i = blockIdx.x * blockDim.x + threadIdx.x;
    int st = gridDim.x * blockDim.x;
    for (; i < n4; i += st) {
        float4 v = reinterpret_cast<const float4*>(x)[i];
        ushort4 o;
        o.x = f2bf(v.x); o.y = f2bf(v.y); o.z = f2bf(v.z); o.w = f2bf(v.w);
        reinterpret_cast<ushort4*>(y)[i] = o;
    }
}

__global__ void cast3_kernel(const float* __restrict__ s0, const float* __restrict__ s1,
                             const float* __restrict__ s2,
                             unsigned short* __restrict__ d0, unsigned short* __restrict__ d1,
                             unsigned short* __restrict__ d2, int n4) {
    const float* s = (blockIdx.y == 0) ? s0 : (blockIdx.y == 1) ? s1 : s2;
    unsigned short* d = (blockIdx.y == 0) ? d0 : (blockIdx.y == 1) ? d1 : d2;
    int i = blockIdx.x * blockDim.x + threadIdx.x;
    int st = gridDim.x * blockDim.x;
    for (; i < n4; i += st) {
        float4 v = reinterpret_cast<const float4*>(s)[i];
        ushort4 o;
        o.x = f2bf(v.x); o.y = f2bf(v.y); o.z = f2bf(v.z); o.w = f2bf(v.w);
        reinterpret_cast<ushort4*>(d)[i] = o;
    }
}

// ------------------------------------------------------- GEMM: C = (A*B^T+b)*s
// (m97-style 128x128, proven; out-projection)
template <typename OUT>
__global__ __launch_bounds__(256) void gemm_bt(
    const unsigned short* __restrict__ A, const unsigned short* __restrict__ Bw,
    const float* __restrict__ bias, OUT* __restrict__ C,
    int M, int N, int K, float scale) {
    __shared__ __align__(16) unsigned short Ash[128 * 32];
    __shared__ __align__(16) unsigned short Bsh[128 * 32];

    const int tid  = threadIdx.x;
    const int lane = tid & 63;
    const int w    = tid >> 6;
    const int g    = lane >> 4;
    const int l15  = lane & 15;
    const int m0   = blockIdx.y * 128;
    const int n0   = blockIdx.x * 128;
    const int wm   = (w >> 1) * 64;
    const int wn   = (w & 1) * 64;

    f32x4 acc[4][4];
#pragma unroll
    for (int i = 0; i < 4; i++)
#pragma unroll
        for (int j = 0; j < 4; j++) acc[i][j] = (f32x4){0.f, 0.f, 0.f, 0.f};

    const int c0 = tid, c1 = tid + 256;
    const int rowA0 = c0 >> 2, colA0 = (c0 & 3) * 8;
    const int rowA1 = c1 >> 2, colA1 = (c1 & 3) * 8;

    for (int k0 = 0; k0 < K; k0 += 32) {
        __syncthreads();
        __builtin_amdgcn_global_load_lds(TO_GLOBAL(A + (size_t)(m0 + rowA0) * K + k0 + colA0),
                                         TO_LDS(&Ash[c0 * 8]), 16, 0, 0);
        __builtin_amdgcn_global_load_lds(TO_GLOBAL(A + (size_t)(m0 + rowA1) * K + k0 + colA1),
                                         TO_LDS(&Ash[c1 * 8]), 16, 0, 0);
        __builtin_amdgcn_global_load_lds(TO_GLOBAL(Bw + (size_t)(n0 + rowA0) * K + k0 + colA0),
                                         TO_LDS(&Bsh[c0 * 8]), 16, 0, 0);
        __builtin_amdgcn_global_load_lds(TO_GLOBAL(Bw + (size_t)(n0 + rowA1) * K + k0 + colA1),
                                         TO_LDS(&Bsh[c1 * 8]), 16, 0, 0);
        __syncthreads();

        bfx8 af[4], bfr[4];
#pragma unroll
        for (int mi = 0; mi < 4; mi++)
            af[mi] = *reinterpret_cast<const bfx8*>(&Ash[(wm + mi * 16 + l15) * 32 + g * 8]);
#pragma unroll
        for (int ni = 0; ni < 4; ni++)
            bfr[ni] = *reinterpret_cast<const bfx8*>(&Bsh[(wn + ni * 16 + l15) * 32 + g * 8]);
#pragma unroll
        for (int mi = 0; mi < 4; mi++)
#pragma unroll
            for (int ni = 0; ni < 4; ni++)
                acc[mi][ni] = __builtin_amdgcn_mfma_f32_16x16x32_bf16(af[mi], bfr[ni],
                                                                     acc[mi][ni], 0, 0, 0);
    }

#pragma unroll
    for (int mi = 0; mi < 4; mi++) {
#pragma unroll
        for (int ni = 0; ni < 4; ni++) {
            const int col = n0 + wn + ni * 16 + l15;
            const float bv = bias[col];
#pragma unroll
            for (int r = 0; r < 4; r++) {
                const int row = m0 + wm + mi * 16 + g * 4 + r;
                store_out(&C[(size_t)row * N + col], (acc[mi][ni][r] + bv) * scale);
            }
        }
    }
}

// -------------------------------------------- fused QKV GEMM (gridDim.z = 3)
// z==0/1 -> Q/K row-major [4096][2048]. z==2 -> V transposed through LDS:
// epilogue stages each 64-row half into a 16KB swizzled LDS tile, then all
// threads write Vt[(b*2048+d)][s] with 16B runs along s (coalesced).
__global__ __launch_bounds__(256) void gemm_qkv(
    const unsigned short* __restrict__ A,
    const unsigned short* __restrict__ W0, const unsigned short* __restrict__ W1,
    const unsigned short* __restrict__ W2,
    const float* __restrict__ b0, const float* __restrict__ b1,
    const float* __restrict__ b2,
    unsigned short* __restrict__ C0, unsigned short* __restrict__ C1,
    unsigned short* __restrict__ C2, float qks) {
    const int z = blockIdx.z;
    const unsigned short* Bw = (z == 0) ? W0 : (z == 1) ? W1 : W2;
    const float* bias = (z == 0) ? b0 : (z == 1) ? b1 : b2;
    unsigned short* C = (z == 0) ? C0 : (z == 1) ? C1 : C2;
    const float scale = (z < 2) ? qks : 1.0f;
    const int N = 2048, K = 2048;

    __shared__ __align__(16) unsigned short S[8192];   // 16 KB: staging / transpose
    unsigned short* Ash = S;            // 128*32
    unsigned short* Bsh = S + 4096;     // 128*32

    const int tid  = threadIdx.x;
    const int lane = tid & 63;
    const int w    = tid >> 6;
    const int g    = lane >> 4;
    const int l15  = lane & 15;
    const int m0   = blockIdx.y * 128;
    const int n0   = blockIdx.x * 128;
    const int wm   = (w >> 1) * 64;
    const int wn   = (w & 1) * 64;

    f32x4 acc[4][4];
#pragma unroll
    for (int i = 0; i < 4; i++)
#pragma unroll
        for (int j = 0; j < 4; j++) acc[i][j] = (f32x4){0.f, 0.f, 0.f, 0.f};

    const int c0 = tid, c1 = tid + 256;
    const int rowA0 = c0 >> 2, colA0 = (c0 & 3) * 8;
    const int rowA1 = c1 >> 2, colA1 = (c1 & 3) * 8;

    for (int k0 = 0; k0 < K; k0 += 32) {
        __syncthreads();
        __builtin_amdgcn_global_load_lds(TO_GLOBAL(A + (size_t)(m0 + rowA0) * K + k0 + colA0),
                                         TO_LDS(&Ash[c0 * 8]), 16, 0, 0);
        __builtin_amdgcn_global_load_lds(TO_GLOBAL(A + (size_t)(m0 + rowA1) * K + k0 + colA1),
                                         TO_LDS(&Ash[c1 * 8]), 16, 0, 0);
        __builtin_amdgcn_global_load_lds(TO_GLOBAL(Bw + (size_t)(n0 + rowA0) * K + k0 + colA0),
                                         TO_LDS(&Bsh[c0 * 8]), 16, 0, 0);
        __builtin_amdgcn_global_load_lds(TO_GLOBAL(Bw + (size_t)(n0 + rowA1) * K + k0 + colA1),
                                         TO_LDS(&Bsh[c1 * 8]), 16, 0, 0);
        __syncthreads();

        bfx8 af[4], bfr[4];
#pragma unroll
        for (int mi = 0; mi < 4; mi++)
            af[mi] = *reinterpret_cast<const bfx8*>(&Ash[(wm + mi * 16 + l15) * 32 + g * 8]);
#pragma unroll
        for (int ni = 0; ni < 4; ni++)
            bfr[ni] = *reinterpret_cast<const bfx8*>(&Bsh[(wn + ni * 16 + l15) * 32 + g * 8]);
#pragma unroll
        for (int mi = 0; mi < 4; mi++)
#pragma unroll
            for (int ni = 0; ni < 4; ni++)
                acc[mi][ni] = __builtin_amdgcn_mfma_f32_16x16x32_bf16(af[mi], bfr[ni],
                                                                     acc[mi][ni], 0, 0, 0);
    }

    if (z == 2) {
        // ---- V: transpose through LDS, write Vt[(b*2048 + d)][s] coalesced
        __syncthreads();   // staging reads done; reuse S as tile[64][128]
        unsigned short (*T)[128] = reinterpret_cast<unsigned short(*)[128]>(S);
        const int b_ = m0 >> 11;
        const int sb0 = m0 & 2047;
        const int td  = tid >> 1;           // d 0..127
        const int ts0 = (tid & 1) * 32;     // s chunk base
        unsigned short* dst0 = C + ((size_t)(b_ * 2048 + n0 + td)) * 2048 + sb0 + ts0;
#pragma unroll
        for (int h = 0; h < 2; ++h) {
            if ((w >> 1) == h) {
#pragma unroll
                for (int mi = 0; mi < 4; mi++) {
#pragma unroll
                    for (int ni = 0; ni < 4; ni++) {
                        const int col = wn + ni * 16 + l15;        // local d
                        const float bv = bias[n0 + col];
#pragma unroll
                        for (int r = 0; r < 4; r++) {
                            const int s = mi * 16 + g * 4 + r;     // local s 0..63
                            T[s][col ^ ((s & 7) << 3)] = f2bf(acc[mi][ni][r] + bv);
                        }
                    }
                }
            }
            __syncthreads();
#pragma unroll
            for (int i = 0; i < 4; ++i) {
                bfx8 o;
#pragma unroll
                for (int j = 0; j < 8; ++j) {
                    const int s = ts0 + i * 8 + j;
                    o[j] = (short)T[s][td ^ ((s & 7) << 3)];
                }
                *reinterpret_cast<bfx8*>(dst0 + h * 64 + i * 8) = o;
            }
            __syncthreads();
        }
    } else {
#pragma unroll
        for (int mi = 0; mi < 4; mi++) {
#pragma unroll
            for (int ni = 0; ni < 4; ni++) {
                const int col = n0 + wn + ni * 16 + l15;
                const float bv = bias[col];
#pragma unroll
                for (int r = 0; r < 4; r++) {
                    const int row = m0 + wm + mi * 16 + g * 4 + r;
                    C[(size_t)row * N + col] = f2bf((acc[mi][ni][r] + bv) * scale);
                }
            }
        }
    }
}

// ------------------------------------------------------------ flash attention
// (R8 structure) 4 waves/block, 64 q-rows, paired (p,31-p), single-buffer
// LDS + register staging, fixed-max softmax p = exp2(s - 8*log2e).
#define SLEN 2048
#define DMODEL 2048
#define M2FIX 11.541560327f   /* 8 * log2(e) */

__global__ __launch_bounds__(256, 3) void attn_kernel(
    const unsigned short* __restrict__ Q, const unsigned short* __restrict__ Kp,
    const unsigned short* __restrict__ Vt, unsigned short* __restrict__ O) {
    __shared__ __align__(16) unsigned short Ksh[64 * 128];   // 16 KB, swizzled
    __shared__ __align__(16) unsigned short Vsh[128 * 64];   // 16 KB, swizzled
    __shared__ __align__(16) unsigned short Psh[4 * 1024];   // 8 KB, per-wave P

    const int tid  = threadIdx.x;
    const int lane = tid & 63;
    const int w    = tid >> 6;
    const int g    = lane >> 4;
    const int l15  = lane & 15;
    const int bh   = blockIdx.x;
    const int b    = bh >> 4, h = bh & 15;
    const int pr   = blockIdx.y;             // pair index 0..15

    const size_t bhbase = (size_t)b * SLEN * DMODEL + (size_t)h * 128;
    const size_t vtbase = (size_t)bh * 128 * SLEN;

    unsigned short* Pw = &Psh[w * 1024];
    const int khi_b = l15 >> 3, klo = l15 & 7;
    const int vsw = l15 & 7;

    const int krow = tid >> 4, kch = tid & 15;   // K: 4 iters of +16 rows
    const int vdr  = tid >> 3, vch = tid & 7;    // V: 4 iters of +32 d-rows

    bfx8 kreg[4], vreg[4];

#define LOADREGS(KB)                                                                \
    {                                                                               \
        _Pragma("unroll")                                                           \
        for (int i_ = 0; i_ < 4; i_++)                                              \
            kreg[i_] = *reinterpret_cast<const bfx8*>(                              \
                Kp + bhbase + (size_t)((KB) + krow + 16 * i_) * DMODEL + kch * 8);  \
        _Pragma("unroll")                                                           \
        for (int i_ = 0; i_ < 4; i_++)                                              \
            vreg[i_] = *reinterpret_cast<const bfx8*>(                              \
                Vt + vtbase + (size_t)(vdr + 32 * i_) * SLEN + (KB) + vch * 8);     \
    }

#pragma unroll 1
    for (int seg = 0; seg < 2; seg++) {
        const int qt  = seg == 0 ? (31 - pr) : pr;       // 64-row q-tile index
        const int q0w = qt * 64 + w * 16;

        bfx8 qf[4];
#pragma unroll
        for (int c = 0; c < 4; c++)
            qf[c] = *reinterpret_cast<const bfx8*>(
                Q + bhbase + (size_t)(q0w + l15) * DMODEL + c * 32 + g * 8);

        f32x4 oacc[8];
#pragma unroll
        for (int i = 0; i < 8; i++) oacc[i] = (f32x4){0.f, 0.f, 0.f, 0.f};
        float lpart[4] = {0.f, 0.f, 0.f, 0.f};

        const int ntile = qt + 1;
        LOADREGS(0);

#pragma unroll 1
        for (int t = 0; t < ntile; t++) {
            const int kb = t * 64;
            __builtin_amdgcn_s_barrier();          // A: all waves done reading LDS
            __builtin_amdgcn_sched_barrier(0);
#pragma unroll
            for (int i = 0; i < 4; i++) {
                const int row = krow + 16 * i;
                *reinterpret_cast<bfx8*>(&Ksh[row * 128 + ((kch ^ (row & 7)) * 8)]) = kreg[i];
            }
#pragma unroll
            for (int i = 0; i < 4; i++) {
                const int dr = vdr + 32 * i;
                *reinterpret_cast<bfx8*>(&Vsh[dr * 64 + ((vch ^ (dr & 7)) * 8)]) = vreg[i];
            }
            asm volatile("s_waitcnt lgkmcnt(0)" ::: "memory");
            __builtin_amdgcn_s_barrier();          // B: tile t ready
            __builtin_amdgcn_sched_barrier(0);
            if (t + 1 < ntile) LOADREGS(kb + 64);

            __builtin_amdgcn_s_setprio(1);
            f32x4 sacc[4];
#pragma unroll
            for (int kt = 0; kt < 4; kt++) sacc[kt] = (f32x4){0.f, 0.f, 0.f, 0.f};
#pragma unroll
            for (int kt = 0; kt < 4; kt++) {
                const int row = kt * 16 + l15;
#pragma unroll
                for (int c = 0; c < 4; c++) {
                    bfx8 kf = *reinterpret_cast<const bfx8*>(
                        &Ksh[row * 128 + (((c * 4 + g) ^ (row & 7)) * 8)]);
                    sacc[kt] = __builtin_amdgcn_mfma_f32_16x16x32_bf16(
                        qf[c], kf, sacc[kt], 0, 0, 0);
                }
            }
            __builtin_amdgcn_s_setprio(0);
            if (t == ntile - 1) {
#pragma unroll
                for (int kt = 0; kt < 4; kt++)
#pragma unroll
                    for (int r = 0; r < 4; r++)
                        if (kb + kt * 16 + l15 > q0w + g * 4 + r)
                            sacc[kt][r] = -1e30f;
            }
#pragma unroll
            for (int r = 0; r < 4; r++) {
                const float p0 = exp2f(sacc[0][r] - M2FIX);
                const float p1 = exp2f(sacc[1][r] - M2FIX);
                const float p2 = exp2f(sacc[2][r] - M2FIX);
                const float p3 = exp2f(sacc[3][r] - M2FIX);
                lpart[r] += (p0 + p1) + (p2 + p3);
                const int ql = g * 4 + r;
                const int swz = ql & 7;
                Pw[ql * 64 + (((khi_b + 0) ^ swz) << 3) + klo] = f2bf(p0);
                Pw[ql * 64 + (((khi_b + 2) ^ swz) << 3) + klo] = f2bf(p1);
                Pw[ql * 64 + (((khi_b + 4) ^ swz) << 3) + klo] = f2bf(p2);
                Pw[ql * 64 + (((khi_b + 6) ^ swz) << 3) + klo] = f2bf(p3);
            }
            __builtin_amdgcn_s_setprio(1);
#pragma unroll
            for (int ks = 0; ks < 2; ks++) {
                bfx8 vb[8];
#pragma unroll
                for (int ni = 0; ni < 8; ni++) {
                    const int d = ni * 16 + l15;
                    vb[ni] = *reinterpret_cast<const bfx8*>(
                        &Vsh[d * 64 + (((ks * 4 + g) ^ vsw) * 8)]);
                }
                bfx8 pa = *reinterpret_cast<const bfx8*>(
                    Pw + l15 * 64 + (((ks * 4 + g) ^ vsw) << 3));
#pragma unroll
                for (int ni = 0; ni < 8; ni++)
                    oacc[ni] = __builtin_amdgcn_mfma_f32_16x16x32_bf16(
                        pa, vb[ni], oacc[ni], 0, 0, 0);
            }
            __builtin_amdgcn_s_setprio(0);
        }

#pragma unroll
        for (int r = 0; r < 4; r++) {
            float l = lpart[r];
#pragma unroll
            for (int s = 1; s < 16; s <<= 1) l += __shfl_xor(l, s);
            const float inv = 1.0f / l;
            const int q = q0w + g * 4 + r;
#pragma unroll
            for (int ni = 0; ni < 8; ni++)
                O[bhbase + (size_t)q * DMODEL + ni * 16 + l15] = f2bf(oacc[ni][r] * inv);
        }
    }
#undef LOADREGS
}

// ---------------------------------------------------------------------------
extern "C" void kernel_launch(void* const* d_in, const int* in_sizes, int n_in,
                              void* d_out, int out_size, void* d_ws, size_t ws_size,
                              hipStream_t stream) {
    const float* X  = (const float*)d_in[0];
    const float* Wq = (const float*)d_in[1];
    const float* bq = (const float*)d_in[2];
    const float* Wk = (const float*)d_in[3];
    const float* bk = (const float*)d_in[4];
    const float* Wv = (const float*)d_in[5];
    const float* bv = (const float*)d_in[6];
    const float* Wo = (const float*)d_in[7];
    const float* bo = (const float*)d_in[8];
    float* out = (float*)d_out;

    // workspace layout (bf16 elements): Q | K | Vt | X(->attn O) | Wstage
    unsigned short* ws  = (unsigned short*)d_ws;
    unsigned short* Qb  = ws;
    unsigned short* Kb  = ws + 8388608;
    unsigned short* Vtb = ws + 16777216;
    unsigned short* XOb = ws + 25165824;   // X bf16, reused as attention output
    unsigned short* Wb  = ws + 33554432;   // weight staging (4M elems)
    // scratch carved from d_out (overwritten by the final GEMM):
    unsigned short* out_u = (unsigned short*)d_out;
    unsigned short* Wkb   = out_u;                 // Wk bf16
    unsigned short* Wvb   = out_u + 4194304;       // Wv bf16

    // 128^(-1/4) * sqrt(log2 e): folds the exp->exp2 conversion into Q,K
    const float qk_scale = 0.35709585f;

    const dim3 cb(256);

    cast_bf16_kernel<<<dim3(2048), cb, 0, stream>>>(X, XOb, 2097152);
    cast3_kernel<<<dim3(1024, 3), cb, 0, stream>>>(Wq, Wk, Wv, Wb, Wkb, Wvb, 1048576);

    gemm_qkv<<<dim3(16, 32, 3), cb, 0, stream>>>(XOb, Wb, Wkb, Wvb, bq, bk, bv,
                                                 Qb, Kb, Vtb, qk_scale);

    attn_kernel<<<dim3(32, 16), cb, 0, stream>>>(Qb, Kb, Vtb, XOb);

    cast_bf16_kernel<<<dim3(1024), cb, 0, stream>>>(Wo, Wb, 1048576);
    gemm_bt<float><<<dim3(16, 32), cb, 0, stream>>>(XOb, Wb, bo, out, 4096, 2048, 2048, 1.0f);
}

// Round 14
// 281.262 us; speedup vs baseline: 1.0407x; 1.0407x over previous
//
#include <hip/hip_runtime.h>

// ---------------------------------------------------------------------------
// MultiHeadedDotProductSelfAttention: B=2, S=2048, D=2048, H=16, dh=128
// R14: exact restore of R8 (best measured: 282.5 us). 128^2 fused qkv GEMM,
// separate transpose_v, attn = 3 blocks/CU reg-staged LDS + fixed-max softmax,
// out-proj = proven gemm_bt<float>. No experimental deltas.
// ---------------------------------------------------------------------------

typedef __attribute__((ext_vector_type(8))) short bfx8;
typedef __attribute__((ext_vector_type(4))) float f32x4;

#define TO_GLOBAL(p) ((const __attribute__((address_space(1))) void*)(p))
#define TO_LDS(p)    ((__attribute__((address_space(3))) void*)(p))

__device__ __forceinline__ unsigned short f2bf(float f) {
    unsigned int u = __float_as_uint(f);
    u += 0x7FFFu + ((u >> 16) & 1u);          // round-to-nearest-even
    return (unsigned short)(u >> 16);
}

__device__ __forceinline__ void store_out(unsigned short* p, float v) { *p = f2bf(v); }
__device__ __forceinline__ void store_out(float* p, float v) { *p = v; }

// ---------------------------------------------------------------- cast kernels
__global__ void cast_bf16_kernel(const float* __restrict__ x,
                                 unsigned short* __restrict__ y, int n4) {
    int i = blockIdx.x * blockDim.x + threadIdx.x;
    int st = gridDim.x * blockDim.x;
    for (; i < n4; i += st) {
        float4 v = reinterpret_cast<const float4*>(x)[i];
        ushort4 o;
        o.x = f2bf(v.x); o.y = f2bf(v.y); o.z = f2bf(v.z); o.w = f2bf(v.w);
        reinterpret_cast<ushort4*>(y)[i] = o;
    }
}

__global__ void cast3_kernel(const float* __restrict__ s0, const float* __restrict__ s1,
                             const float* __restrict__ s2,
                             unsigned short* __restrict__ d0, unsigned short* __restrict__ d1,
                             unsigned short* __restrict__ d2, int n4) {
    const float* s = (blockIdx.y == 0) ? s0 : (blockIdx.y == 1) ? s1 : s2;
    unsigned short* d = (blockIdx.y == 0) ? d0 : (blockIdx.y == 1) ? d1 : d2;
    int i = blockIdx.x * blockDim.x + threadIdx.x;
    int st = gridDim.x * blockDim.x;
    for (; i < n4; i += st) {
        float4 v = reinterpret_cast<const float4*>(s)[i];
        ushort4 o;
        o.x = f2bf(v.x); o.y = f2bf(v.y); o.z = f2bf(v.z); o.w = f2bf(v.w);
        reinterpret_cast<ushort4*>(d)[i] = o;
    }
}

// ------------------------------------------------------- GEMM: C = (A*B^T+b)*s
template <typename OUT>
__global__ __launch_bounds__(256) void gemm_bt(
    const unsigned short* __restrict__ A, const unsigned short* __restrict__ Bw,
    const float* __restrict__ bias, OUT* __restrict__ C,
    int M, int N, int K, float scale) {
    __shared__ __align__(16) unsigned short Ash[128 * 32];
    __shared__ __align__(16) unsigned short Bsh[128 * 32];

    const int tid  = threadIdx.x;
    const int lane = tid & 63;
    const int w    = tid >> 6;
    const int g    = lane >> 4;
    const int l15  = lane & 15;
    const int m0   = blockIdx.y * 128;
    const int n0   = blockIdx.x * 128;
    const int wm   = (w >> 1) * 64;
    const int wn   = (w & 1) * 64;

    f32x4 acc[4][4];
#pragma unroll
    for (int i = 0; i < 4; i++)
#pragma unroll
        for (int j = 0; j < 4; j++) acc[i][j] = (f32x4){0.f, 0.f, 0.f, 0.f};

    const int c0 = tid, c1 = tid + 256;
    const int rowA0 = c0 >> 2, colA0 = (c0 & 3) * 8;
    const int rowA1 = c1 >> 2, colA1 = (c1 & 3) * 8;

    for (int k0 = 0; k0 < K; k0 += 32) {
        __syncthreads();
        __builtin_amdgcn_global_load_lds(TO_GLOBAL(A + (size_t)(m0 + rowA0) * K + k0 + colA0),
                                         TO_LDS(&Ash[c0 * 8]), 16, 0, 0);
        __builtin_amdgcn_global_load_lds(TO_GLOBAL(A + (size_t)(m0 + rowA1) * K + k0 + colA1),
                                         TO_LDS(&Ash[c1 * 8]), 16, 0, 0);
        __builtin_amdgcn_global_load_lds(TO_GLOBAL(Bw + (size_t)(n0 + rowA0) * K + k0 + colA0),
                                         TO_LDS(&Bsh[c0 * 8]), 16, 0, 0);
        __builtin_amdgcn_global_load_lds(TO_GLOBAL(Bw + (size_t)(n0 + rowA1) * K + k0 + colA1),
                                         TO_LDS(&Bsh[c1 * 8]), 16, 0, 0);
        __syncthreads();

        bfx8 af[4], bfr[4];
#pragma unroll
        for (int mi = 0; mi < 4; mi++)
            af[mi] = *reinterpret_cast<const bfx8*>(&Ash[(wm + mi * 16 + l15) * 32 + g * 8]);
#pragma unroll
        for (int ni = 0; ni < 4; ni++)
            bfr[ni] = *reinterpret_cast<const bfx8*>(&Bsh[(wn + ni * 16 + l15) * 32 + g * 8]);
#pragma unroll
        for (int mi = 0; mi < 4; mi++)
#pragma unroll
            for (int ni = 0; ni < 4; ni++)
                acc[mi][ni] = __builtin_amdgcn_mfma_f32_16x16x32_bf16(af[mi], bfr[ni],
                                                                     acc[mi][ni], 0, 0, 0);
    }

#pragma unroll
    for (int mi = 0; mi < 4; mi++) {
#pragma unroll
        for (int ni = 0; ni < 4; ni++) {
            const int col = n0 + wn + ni * 16 + l15;
            const float bv = bias[col];
#pragma unroll
            for (int r = 0; r < 4; r++) {
                const int row = m0 + wm + mi * 16 + g * 4 + r;
                store_out(&C[(size_t)row * N + col], (acc[mi][ni][r] + bv) * scale);
            }
        }
    }
}

// -------------------------------------------- fused QKV GEMM (gridDim.z = 3)
__global__ __launch_bounds__(256) void gemm_qkv(
    const unsigned short* __restrict__ A,
    const unsigned short* __restrict__ W0, const unsigned short* __restrict__ W1,
    const unsigned short* __restrict__ W2,
    const float* __restrict__ b0, const float* __restrict__ b1,
    const float* __restrict__ b2,
    unsigned short* __restrict__ C0, unsigned short* __restrict__ C1,
    unsigned short* __restrict__ C2, float qks) {
    const int z = blockIdx.z;
    const unsigned short* Bw = (z == 0) ? W0 : (z == 1) ? W1 : W2;
    const float* bias = (z == 0) ? b0 : (z == 1) ? b1 : b2;
    unsigned short* C = (z == 0) ? C0 : (z == 1) ? C1 : C2;
    const float scale = (z < 2) ? qks : 1.0f;
    const int N = 2048, K = 2048;

    __shared__ __align__(16) unsigned short Ash[128 * 32];
    __shared__ __align__(16) unsigned short Bsh[128 * 32];

    const int tid  = threadIdx.x;
    const int lane = tid & 63;
    const int w    = tid >> 6;
    const int g    = lane >> 4;
    const int l15  = lane & 15;
    const int m0   = blockIdx.y * 128;
    const int n0   = blockIdx.x * 128;
    const int wm   = (w >> 1) * 64;
    const int wn   = (w & 1) * 64;

    f32x4 acc[4][4];
#pragma unroll
    for (int i = 0; i < 4; i++)
#pragma unroll
        for (int j = 0; j < 4; j++) acc[i][j] = (f32x4){0.f, 0.f, 0.f, 0.f};

    const int c0 = tid, c1 = tid + 256;
    const int rowA0 = c0 >> 2, colA0 = (c0 & 3) * 8;
    const int rowA1 = c1 >> 2, colA1 = (c1 & 3) * 8;

    for (int k0 = 0; k0 < K; k0 += 32) {
        __syncthreads();
        __builtin_amdgcn_global_load_lds(TO_GLOBAL(A + (size_t)(m0 + rowA0) * K + k0 + colA0),
                                         TO_LDS(&Ash[c0 * 8]), 16, 0, 0);
        __builtin_amdgcn_global_load_lds(TO_GLOBAL(A + (size_t)(m0 + rowA1) * K + k0 + colA1),
                                         TO_LDS(&Ash[c1 * 8]), 16, 0, 0);
        __builtin_amdgcn_global_load_lds(TO_GLOBAL(Bw + (size_t)(n0 + rowA0) * K + k0 + colA0),
                                         TO_LDS(&Bsh[c0 * 8]), 16, 0, 0);
        __builtin_amdgcn_global_load_lds(TO_GLOBAL(Bw + (size_t)(n0 + rowA1) * K + k0 + colA1),
                                         TO_LDS(&Bsh[c1 * 8]), 16, 0, 0);
        __syncthreads();

        bfx8 af[4], bfr[4];
#pragma unroll
        for (int mi = 0; mi < 4; mi++)
            af[mi] = *reinterpret_cast<const bfx8*>(&Ash[(wm + mi * 16 + l15) * 32 + g * 8]);
#pragma unroll
        for (int ni = 0; ni < 4; ni++)
            bfr[ni] = *reinterpret_cast<const bfx8*>(&Bsh[(wn + ni * 16 + l15) * 32 + g * 8]);
#pragma unroll
        for (int mi = 0; mi < 4; mi++)
#pragma unroll
            for (int ni = 0; ni < 4; ni++)
                acc[mi][ni] = __builtin_amdgcn_mfma_f32_16x16x32_bf16(af[mi], bfr[ni],
                                                                     acc[mi][ni], 0, 0, 0);
    }

#pragma unroll
    for (int mi = 0; mi < 4; mi++) {
#pragma unroll
        for (int ni = 0; ni < 4; ni++) {
            const int col = n0 + wn + ni * 16 + l15;
            const float bv = bias[col];
#pragma unroll
            for (int r = 0; r < 4; r++) {
                const int row = m0 + wm + mi * 16 + g * 4 + r;
                C[(size_t)row * N + col] = f2bf((acc[mi][ni][r] + bv) * scale);
            }
        }
    }
}

// ------------------------------------------------- V transpose: [bs][d] -> [d'][s]
__global__ __launch_bounds__(256) void transpose_v(const unsigned short* __restrict__ V,
                                                   unsigned short* __restrict__ Vt) {
    __shared__ unsigned short tile[64][72];
    const int tid = threadIdx.x;
    const int r0 = blockIdx.y * 64;          // token-tile base
    const int c0 = blockIdx.x * 64;          // model-dim tile base
    const int b = r0 >> 11, sbase = r0 & 2047;
#pragma unroll
    for (int i = 0; i < 2; i++) {
        const int row = tid >> 2;
        const int ch  = (tid & 3) + 4 * i;
        bfx8 v = *reinterpret_cast<const bfx8*>(V + (size_t)(r0 + row) * 2048 + c0 + ch * 8);
        *reinterpret_cast<bfx8*>(&tile[row][ch * 8]) = v;
    }
    __syncthreads();
    const int dh  = tid & 63;
    const int s_l = (tid >> 6) * 16;
    unsigned short* dst = Vt + (size_t)(b * 2048 + c0 + dh) * 2048 + sbase + s_l;
#pragma unroll
    for (int half = 0; half < 2; half++) {
        bfx8 o;
#pragma unroll
        for (int j = 0; j < 8; j++) o[j] = (short)tile[s_l + half * 8 + j][dh];
        *reinterpret_cast<bfx8*>(dst + half * 8) = o;
    }
}

// ------------------------------------------------------------ flash attention
// Q,K,O: [B][S][H][dh] bf16 (Q,K pre-scaled by 128^-.25 * sqrt(log2e)).
// Vt: [bh][dh][s]. 4 waves/block, 64 q-rows/block (16 per wave). Paired
// q-tiles (p, 31-p) -> uniform 33 KV tiles/block; 512 blocks, 3/CU (40KB LDS).
// Single-buffer LDS + register staging; fixed-max softmax p = exp2(s-8*log2e).
#define SLEN 2048
#define DMODEL 2048
#define M2FIX 11.541560327f   /* 8 * log2(e) */

__global__ __launch_bounds__(256, 3) void attn_kernel(
    const unsigned short* __restrict__ Q, const unsigned short* __restrict__ Kp,
    const unsigned short* __restrict__ Vt, unsigned short* __restrict__ O) {
    __shared__ __align__(16) unsigned short Ksh[64 * 128];   // 16 KB, swizzled
    __shared__ __align__(16) unsigned short Vsh[128 * 64];   // 16 KB, swizzled
    __shared__ __align__(16) unsigned short Psh[4 * 1024];   // 8 KB, per-wave P

    const int tid  = threadIdx.x;
    const int lane = tid & 63;
    const int w    = tid >> 6;
    const int g    = lane >> 4;
    const int l15  = lane & 15;
    const int bh   = blockIdx.x;
    const int b    = bh >> 4, h = bh & 15;
    const int pr   = blockIdx.y;             // pair index 0..15

    const size_t bhbase = (size_t)b * SLEN * DMODEL + (size_t)h * 128;
    const size_t vtbase = (size_t)bh * 128 * SLEN;

    unsigned short* Pw = &Psh[w * 1024];
    const int khi_b = l15 >> 3, klo = l15 & 7;
    const int vsw = l15 & 7;

    const int krow = tid >> 4, kch = tid & 15;   // K: 4 iters of +16 rows
    const int vdr  = tid >> 3, vch = tid & 7;    // V: 4 iters of +32 d-rows

    bfx8 kreg[4], vreg[4];

#define LOADREGS(KB)                                                                \
    {                                                                               \
        _Pragma("unroll")                                                           \
        for (int i_ = 0; i_ < 4; i_++)                                              \
            kreg[i_] = *reinterpret_cast<const bfx8*>(                              \
                Kp + bhbase + (size_t)((KB) + krow + 16 * i_) * DMODEL + kch * 8);  \
        _Pragma("unroll")                                                           \
        for (int i_ = 0; i_ < 4; i_++)                                              \
            vreg[i_] = *reinterpret_cast<const bfx8*>(                              \
                Vt + vtbase + (size_t)(vdr + 32 * i_) * SLEN + (KB) + vch * 8);     \
    }

#pragma unroll 1
    for (int seg = 0; seg < 2; seg++) {
        const int qt  = seg == 0 ? (31 - pr) : pr;       // 64-row q-tile index
        const int q0w = qt * 64 + w * 16;

        bfx8 qf[4];
#pragma unroll
        for (int c = 0; c < 4; c++)
            qf[c] = *reinterpret_cast<const bfx8*>(
                Q + bhbase + (size_t)(q0w + l15) * DMODEL + c * 32 + g * 8);

        f32x4 oacc[8];
#pragma unroll
        for (int i = 0; i < 8; i++) oacc[i] = (f32x4){0.f, 0.f, 0.f, 0.f};
        float lpart[4] = {0.f, 0.f, 0.f, 0.f};

        const int ntile = qt + 1;
        LOADREGS(0);

#pragma unroll 1
        for (int t = 0; t < ntile; t++) {
            const int kb = t * 64;
            __builtin_amdgcn_s_barrier();          // A: all waves done reading LDS
            __builtin_amdgcn_sched_barrier(0);
#pragma unroll
            for (int i = 0; i < 4; i++) {
                const int row = krow + 16 * i;
                *reinterpret_cast<bfx8*>(&Ksh[row * 128 + ((kch ^ (row & 7)) * 8)]) = kreg[i];
            }
#pragma unroll
            for (int i = 0; i < 4; i++) {
                const int dr = vdr + 32 * i;
                *reinterpret_cast<bfx8*>(&Vsh[dr * 64 + ((vch ^ (dr & 7)) * 8)]) = vreg[i];
            }
            asm volatile("s_waitcnt lgkmcnt(0)" ::: "memory");
            __builtin_amdgcn_s_barrier();          // B: tile t ready
            __builtin_amdgcn_sched_barrier(0);
            if (t + 1 < ntile) LOADREGS(kb + 64);

            __builtin_amdgcn_s_setprio(1);
            f32x4 sacc[4];
#pragma unroll
            for (int kt = 0; kt < 4; kt++) sacc[kt] = (f32x4){0.f, 0.f, 0.f, 0.f};
#pragma unroll
            for (int kt = 0; kt < 4; kt++) {
                const int row = kt * 16 + l15;
#pragma unroll
                for (int c = 0; c < 4; c++) {
                    bfx8 kf = *reinterpret_cast<const bfx8*>(
                        &Ksh[row * 128 + (((c * 4 + g) ^ (row & 7)) * 8)]);
                    sacc[kt] = __builtin_amdgcn_mfma_f32_16x16x32_bf16(
                        qf[c], kf, sacc[kt], 0, 0, 0);
                }
            }
            __builtin_amdgcn_s_setprio(0);
            if (t == ntile - 1) {
#pragma unroll
                for (int kt = 0; kt < 4; kt++)
#pragma unroll
                    for (int r = 0; r < 4; r++)
                        if (kb + kt * 16 + l15 > q0w + g * 4 + r)
                            sacc[kt][r] = -1e30f;
            }
#pragma unroll
            for (int r = 0; r < 4; r++) {
                const float p0 = exp2f(sacc[0][r] - M2FIX);
                const float p1 = exp2f(sacc[1][r] - M2FIX);
                const float p2 = exp2f(sacc[2][r] - M2FIX);
                const float p3 = exp2f(sacc[3][r] - M2FIX);
                lpart[r] += (p0 + p1) + (p2 + p3);
                const int ql = g * 4 + r;
                const int swz = ql & 7;
                Pw[ql * 64 + (((khi_b + 0) ^ swz) << 3) + klo] = f2bf(p0);
                Pw[ql * 64 + (((khi_b + 2) ^ swz) << 3) + klo] = f2bf(p1);
                Pw[ql * 64 + (((khi_b + 4) ^ swz) << 3) + klo] = f2bf(p2);
                Pw[ql * 64 + (((khi_b + 6) ^ swz) << 3) + klo] = f2bf(p3);
            }
            __builtin_amdgcn_s_setprio(1);
#pragma unroll
            for (int ks = 0; ks < 2; ks++) {
                bfx8 vb[8];
#pragma unroll
                for (int ni = 0; ni < 8; ni++) {
                    const int d = ni * 16 + l15;
                    vb[ni] = *reinterpret_cast<const bfx8*>(
                        &Vsh[d * 64 + (((ks * 4 + g) ^ vsw) * 8)]);
                }
                bfx8 pa = *reinterpret_cast<const bfx8*>(
                    Pw + l15 * 64 + (((ks * 4 + g) ^ vsw) << 3));
#pragma unroll
                for (int ni = 0; ni < 8; ni++)
                    oacc[ni] = __builtin_amdgcn_mfma_f32_16x16x32_bf16(
                        pa, vb[ni], oacc[ni], 0, 0, 0);
            }
            __builtin_amdgcn_s_setprio(0);
        }

#pragma unroll
        for (int r = 0; r < 4; r++) {
            float l = lpart[r];
#pragma unroll
            for (int s = 1; s < 16; s <<= 1) l += __shfl_xor(l, s);
            const float inv = 1.0f / l;
            const int q = q0w + g * 4 + r;
#pragma unroll
            for (int ni = 0; ni < 8; ni++)
                O[bhbase + (size_t)q * DMODEL + ni * 16 + l15] = f2bf(oacc[ni][r] * inv);
        }
    }
#undef LOADREGS
}

// ---------------------------------------------------------------------------
extern "C" void kernel_launch(void* const* d_in, const int* in_sizes, int n_in,
                              void* d_out, int out_size, void* d_ws, size_t ws_size,
                              hipStream_t stream) {
    const float* X  = (const float*)d_in[0];
    const float* Wq = (const float*)d_in[1];
    const float* bq = (const float*)d_in[2];
    const float* Wk = (const float*)d_in[3];
    const float* bk = (const float*)d_in[4];
    const float* Wv = (const float*)d_in[5];
    const float* bv = (const float*)d_in[6];
    const float* Wo = (const float*)d_in[7];
    const float* bo = (const float*)d_in[8];
    float* out = (float*)d_out;

    // workspace layout (bf16 elements): Q | K | Vt | X(->attn O) | Wstage
    unsigned short* ws  = (unsigned short*)d_ws;
    unsigned short* Qb  = ws;
    unsigned short* Kb  = ws + 8388608;
    unsigned short* Vtb = ws + 16777216;
    unsigned short* XOb = ws + 25165824;   // X bf16, reused as attention output
    unsigned short* Wb  = ws + 33554432;   // weight staging (4M elems)
    // scratch carved from d_out (overwritten by the final GEMM):
    unsigned short* out_u   = (unsigned short*)d_out;
    unsigned short* Vstage  = out_u;               // V row-major (8.38M elems)
    unsigned short* Wkb     = out_u + 8388608;     // Wk bf16
    unsigned short* Wvb     = out_u + 12582912;    // Wv bf16

    // 128^(-1/4) * sqrt(log2 e): folds the exp->exp2 conversion into Q,K
    const float qk_scale = 0.35709585f;

    const dim3 cb(256);

    cast_bf16_kernel<<<dim3(2048), cb, 0, stream>>>(X, XOb, 2097152);
    cast3_kernel<<<dim3(1024, 3), cb, 0, stream>>>(Wq, Wk, Wv, Wb, Wkb, Wvb, 1048576);

    gemm_qkv<<<dim3(16, 32, 3), cb, 0, stream>>>(XOb, Wb, Wkb, Wvb, bq, bk, bv,
                                                 Qb, Kb, Vstage, qk_scale);

    transpose_v<<<dim3(32, 64), cb, 0, stream>>>(Vstage, Vtb);

    attn_kernel<<<dim3(32, 16), cb, 0, stream>>>(Qb, Kb, Vtb, XOb);

    cast_bf16_kernel<<<dim3(1024), cb, 0, stream>>>(Wo, Wb, 1048576);
    gemm_bt<float><<<dim3(16, 32), cb, 0, stream>>>(XOb, Wb, bo, out, 4096, 2048, 2048, 1.0f);
}